// Round 3
// baseline (479.632 us; speedup 1.0000x reference)
//
#include <hip/hip_runtime.h>
#include <hip/hip_bf16.h>

// Deformable1DFeatureAggregator on MI355X (gfx950) — round 2
// Kernels:
//   memset(hist)                              (hipMemsetAsync)
//   k_prep    : Ww/Wv/Wo -> bf16 N x K (WwT 80 rows, zero-padded)
//   k_hist    : histogram of (batch, y0) buckets (258)
//   k_scan    : exclusive prefix -> cursor
//   k_scatter : perm[] = pixel ids sorted by (batch, y0)
//   kA        : LN1 + fp32 Wk offsets -> kp; MFMA logits + softmax -> wts bf16
//   kB        : LN2 + gemmV (A=WvT, channel-major acc) -> val bf16
//   k_gather  : y-sorted bilinear gather + group-weighted sum -> aggb bf16
//   k_gemmo   : out = Wo^T-gemm(aggb) + bo -> fp32 (b,c,h,w)
//
// ws layout (bytes):
//   [0)            val   bf16 65536x256   33,554,432
//   [33554432)     aggb  bf16 65536x256   33,554,432
//   [67108864)     wts   bf16 65536x72     9,437,184
//   [76546048)     WwT   bf16 80x256          40,960
//   [76587008)     WvT   bf16 256x256        131,072
//   [76718080)     WoT   bf16 256x256        131,072
//   [76849152)     perm  int32 65536         262,144
//   [77111296)     hist  int32 258 ; cursor int32 258

constexpr int B = 2, C = 256, H = 128, W = 256;
constexpr int HW = H * W;            // 32768
constexpr int P = 9, G = 8;
constexpr int PIX = 32;
constexpr int NPIX = B * HW;         // 65536
constexpr int NBKT = 2 * 129;        // 258

typedef __attribute__((ext_vector_type(8))) __bf16 bf16x8;
typedef __attribute__((ext_vector_type(4))) float f32x4;

static __device__ __forceinline__ unsigned short f2bf(float x) {
    __hip_bfloat16 h = __float2bfloat16(x);
    return *reinterpret_cast<unsigned short*>(&h);
}
static __device__ __forceinline__ unsigned int pack2(float a, float b) {
    return (unsigned int)f2bf(a) | ((unsigned int)f2bf(b) << 16);
}
static __device__ __forceinline__ float bf2f(unsigned short u) {
    return __uint_as_float((unsigned int)u << 16);
}
static __device__ __forceinline__ bf16x8 ldb8g(const unsigned short* p) {
    return *reinterpret_cast<const bf16x8*>(p);
}

// ---------------------------------------------------------------------------
__global__ __launch_bounds__(256) void k_prep(
    const float* __restrict__ Ww, const float* __restrict__ Wv,
    const float* __restrict__ Wo,
    unsigned short* __restrict__ WwT, unsigned short* __restrict__ WvT,
    unsigned short* __restrict__ WoT)
{
    int tid = blockIdx.x * 256 + threadIdx.x;   // 592 blocks
    if (tid < 20480) {
        int n = tid >> 8, k = tid & 255;
        WwT[tid] = f2bf((n < 72) ? Ww[k * 72 + n] : 0.f);
    } else if (tid < 20480 + 65536) {
        int i = tid - 20480;
        int n = i >> 8, k = i & 255;
        WvT[i] = f2bf(Wv[k * 256 + n]);
    } else {
        int i = tid - 86016;
        int n = i >> 8, k = i & 255;
        WoT[i] = f2bf(Wo[k * 256 + n]);
    }
}

// ---------------------------------------------------------------------------
static __device__ __forceinline__ int bucket_of(const float* anchor, int pix) {
    float ay = anchor[(size_t)pix * 2 + 1];
    int y0 = (int)floorf(ay * (float)H - 0.5f);
    y0 = min(max(y0, -1), H - 1);
    return (pix >> 15) * 129 + y0 + 1;
}

__global__ __launch_bounds__(256) void k_hist(
    const float* __restrict__ anchor, int* __restrict__ hist)
{
    int pix = blockIdx.x * 256 + threadIdx.x;
    atomicAdd(&hist[bucket_of(anchor, pix)], 1);
}

__global__ __launch_bounds__(256) void k_scan(
    const int* __restrict__ hist, int* __restrict__ cursor)
{
    __shared__ int h[NBKT];
    int t = threadIdx.x;
    for (int i = t; i < NBKT; i += 256) h[i] = hist[i];
    __syncthreads();
    if (t == 0) {
        int run = 0;
        for (int i = 0; i < NBKT; ++i) { int v = h[i]; cursor[i] = run; run += v; }
    }
}

__global__ __launch_bounds__(256) void k_scatter(
    const float* __restrict__ anchor, int* __restrict__ cursor,
    int* __restrict__ perm)
{
    int pix = blockIdx.x * 256 + threadIdx.x;
    int pos = atomicAdd(&cursor[bucket_of(anchor, pix)], 1);
    perm[pos] = pix;
}

// ---------------------------------------------------------------------------
// kA: LN1 + fp32 Wk offsets -> kp; MFMA logits (80-col WwT) + softmax -> wts bf16
// block: 32 pixels, 256 threads (4 waves)
// ---------------------------------------------------------------------------
__global__ __launch_bounds__(256) void kA(
    const float* __restrict__ feats1, const float* __restrict__ anchor,
    const float* __restrict__ g1, const float* __restrict__ b1,
    const float* __restrict__ Wk, const float* __restrict__ bk,
    const unsigned short* __restrict__ WwT, const float* __restrict__ bw,
    unsigned short* __restrict__ wtsb, float* __restrict__ kp_out)
{
    __shared__ unsigned short Hi[PIX][264];                 // 16,896 B
    __shared__ __align__(16) char smB[20480];               // WkL+red2+red | Lg alias
    __shared__ float meanA[PIX], rstdA[PIX], axL[PIX], ayL[PIX];

    float* WkL  = (float*)smB;              // [256*9]
    float* red2 = (float*)(smB + 9216);     // [8*32*9]  (part,p,pt)
    float* red  = (float*)(smB + 18432);    // [2*8*32]
    float* Lg   = (float*)smB;              // [32*81] (alias, used post-MFMA)

    const int t = threadIdx.x;
    const int p = t & 31;
    const int part = t >> 5;
    const int gpix0 = blockIdx.x * PIX;
    const int b = gpix0 >> 15;
    const int n0 = gpix0 & (HW - 1);
    const float* Fb = feats1 + (size_t)b * C * HW;

    // stage Wk (256x9 fp32) and anchors
    for (int i = t; i < 2304; i += 256) WkL[i] = Wk[i];
    if (t < PIX) {
        axL[t] = anchor[((size_t)gpix0 + t) * 2 + 0];
        ayL[t] = anchor[((size_t)gpix0 + t) * 2 + 1];
    }

    // load feats1 tile into registers: thread (p,part) holds channels part*32..+32 of pixel p
    float x[32];
    #pragma unroll
    for (int i = 0; i < 32; ++i)
        x[i] = Fb[(size_t)(part * 32 + i) * HW + n0 + p];

    float s = 0.f, ss = 0.f;
    #pragma unroll
    for (int i = 0; i < 32; ++i) { s += x[i]; ss += x[i] * x[i]; }
    red[part * 32 + p] = s;
    red[256 + part * 32 + p] = ss;
    __syncthreads();
    if (part == 0) {
        float s2 = 0.f, ss2 = 0.f;
        #pragma unroll
        for (int k = 0; k < 8; ++k) { s2 += red[k * 32 + p]; ss2 += red[256 + k * 32 + p]; }
        float mean = s2 * (1.f / C);
        float var  = ss2 * (1.f / C) - mean * mean;
        meanA[p] = mean; rstdA[p] = rsqrtf(var + 1e-5f);
    }
    __syncthreads();

    {
        float mean = meanA[p], rstd = rstdA[p];
        #pragma unroll
        for (int i = 0; i < 32; ++i) {
            int c = part * 32 + i;
            x[i] = (x[i] - mean) * rstd * g1[c] + b1[c];
        }
    }

    // fp32 Wk partial dots (per thread: 9 pts over its 32 channels)
    {
        float po[9];
        #pragma unroll
        for (int pt = 0; pt < 9; ++pt) po[pt] = 0.f;
        #pragma unroll 4
        for (int i = 0; i < 32; ++i) {
            int c = part * 32 + i;
            float xv = x[i];
            #pragma unroll
            for (int pt = 0; pt < 9; ++pt) po[pt] += xv * WkL[c * 9 + pt];
        }
        #pragma unroll
        for (int pt = 0; pt < 9; ++pt) red2[(part * 32 + p) * 9 + pt] = po[pt];
    }

    // write bf16 x1 to LDS for MFMA
    {
        unsigned int* row = (unsigned int*)&Hi[p][part * 32];
        #pragma unroll
        for (int i = 0; i < 16; ++i) row[i] = pack2(x[2 * i], x[2 * i + 1]);
    }
    __syncthreads();

    // offsets + kp (fp32)
    for (int tau = t; tau < 288; tau += 256) {
        int px = tau & 31, pt = tau >> 5;
        float off = bk[pt];
        #pragma unroll
        for (int k = 0; k < 8; ++k) off += red2[(k * 32 + px) * 9 + pt];
        size_t o = (((size_t)gpix0 + px) * P + pt) * 2;
        kp_out[o] = axL[px] + off;
        kp_out[o + 1] = ayL[px];
    }

    // MFMA logits: M=32 (2 tiles), N=80 (5 tiles); wave w: M-tile w&1, N-tiles
    const int wave = t >> 6, lane = t & 63;
    const int l15 = lane & 15, quad = lane >> 4;
    const int mt = wave & 1;
    const int ntb = (wave >> 1) * 3;              // 0 or 3
    const int ntc = (wave >> 1) ? 2 : 3;          // tiles 0-2 / 3-4

    f32x4 acc[3];
    #pragma unroll
    for (int j = 0; j < 3; ++j) acc[j] = (f32x4){0.f, 0.f, 0.f, 0.f};

    const unsigned short* arow = &Hi[mt * 16 + l15][quad * 8];
    for (int kk = 0; kk < 8; ++kk) {
        bf16x8 a = *reinterpret_cast<const bf16x8*>(arow + kk * 32);
        for (int j = 0; j < 3; ++j) {
            if (j < ntc) {
                bf16x8 bfr = ldb8g(WwT + (size_t)((ntb + j) * 16 + l15) * 256 + quad * 8 + kk * 32);
                acc[j] = __builtin_amdgcn_mfma_f32_16x16x32_bf16(a, bfr, acc[j], 0, 0, 0);
            }
        }
    }
    __syncthreads();   // red2/WkL dead; Lg alias safe now

    #pragma unroll
    for (int j = 0; j < 3; ++j) {
        if (j < ntc) {
            int n = (ntb + j) * 16 + l15;
            if (n < 72) {
                float bwn = bw[n];
                #pragma unroll
                for (int r = 0; r < 4; ++r)
                    Lg[(mt * 16 + quad * 4 + r) * 81 + n] = acc[j][r] + bwn;
            }
        }
    }
    __syncthreads();

    // softmax over P per (pixel, group) -> wts bf16 [pix][g*9+p]
    {
        int px = t >> 3, g = t & 7;
        float m = -1e30f;
        #pragma unroll
        for (int pt = 0; pt < P; ++pt) m = fmaxf(m, Lg[px * 81 + pt * 8 + g]);
        float e[P], sum = 0.f;
        #pragma unroll
        for (int pt = 0; pt < P; ++pt) { e[pt] = __expf(Lg[px * 81 + pt * 8 + g] - m); sum += e[pt]; }
        float inv = 1.f / sum;
        unsigned short* wb = wtsb + ((size_t)gpix0 + px) * 72 + g * 9;
        #pragma unroll
        for (int pt = 0; pt < P; ++pt) wb[pt] = f2bf(e[pt] * inv);
    }
}

// ---------------------------------------------------------------------------
// kB: LN2 + gemmV. A=WvT (channels = D rows) so each lane's 4 accs are 4
// consecutive channels of one pixel -> uint2 stores. block: 32 pixels.
// ---------------------------------------------------------------------------
__global__ __launch_bounds__(256) void kB(
    const float* __restrict__ feats2,
    const float* __restrict__ g2, const float* __restrict__ b2,
    const unsigned short* __restrict__ WvT, const float* __restrict__ bv,
    unsigned short* __restrict__ val)
{
    __shared__ unsigned short Hi[PIX][264];
    __shared__ float red[2][8][PIX];
    __shared__ float meanA[PIX], rstdA[PIX];

    const int t = threadIdx.x;
    const int p = t & 31;
    const int part = t >> 5;
    const int gpix0 = blockIdx.x * PIX;
    const int b = gpix0 >> 15;
    const int n0 = gpix0 & (HW - 1);
    const float* Fb = feats2 + (size_t)b * C * HW;

    float x[32];
    #pragma unroll
    for (int i = 0; i < 32; ++i)
        x[i] = Fb[(size_t)(part * 32 + i) * HW + n0 + p];

    float s = 0.f, ss = 0.f;
    #pragma unroll
    for (int i = 0; i < 32; ++i) { s += x[i]; ss += x[i] * x[i]; }
    red[0][part][p] = s; red[1][part][p] = ss;
    __syncthreads();
    if (part == 0) {
        float s2 = 0.f, ss2 = 0.f;
        #pragma unroll
        for (int k = 0; k < 8; ++k) { s2 += red[0][k][p]; ss2 += red[1][k][p]; }
        float mean = s2 * (1.f / C);
        float var  = ss2 * (1.f / C) - mean * mean;
        meanA[p] = mean; rstdA[p] = rsqrtf(var + 1e-5f);
    }
    __syncthreads();
    {
        float mean = meanA[p], rstd = rstdA[p];
        unsigned int* row = (unsigned int*)&Hi[p][part * 32];
        #pragma unroll
        for (int i = 0; i < 16; ++i) {
            float v0 = (x[2 * i] - mean) * rstd * g2[part * 32 + 2 * i] + b2[part * 32 + 2 * i];
            float v1 = (x[2 * i + 1] - mean) * rstd * g2[part * 32 + 2 * i + 1] + b2[part * 32 + 2 * i + 1];
            row[i] = pack2(v0, v1);
        }
    }
    __syncthreads();

    // MFMA: M = 256 channels (4 tiles per wave at m0=wave*64), N = 32 pixels (2 tiles)
    const int wave = t >> 6, lane = t & 63;
    const int l15 = lane & 15, quad = lane >> 4;
    const int m0 = wave * 64;

    f32x4 acc[4][2];
    #pragma unroll
    for (int ms = 0; ms < 4; ++ms)
        #pragma unroll
        for (int nt = 0; nt < 2; ++nt)
            acc[ms][nt] = (f32x4){0.f, 0.f, 0.f, 0.f};

    for (int kk = 0; kk < 8; ++kk) {
        bf16x8 a[4], bfr[2];
        #pragma unroll
        for (int ms = 0; ms < 4; ++ms)
            a[ms] = ldb8g(WvT + (size_t)(m0 + ms * 16 + l15) * 256 + quad * 8 + kk * 32);
        #pragma unroll
        for (int nt = 0; nt < 2; ++nt)
            bfr[nt] = *reinterpret_cast<const bf16x8*>(&Hi[nt * 16 + l15][quad * 8 + kk * 32]);
        #pragma unroll
        for (int ms = 0; ms < 4; ++ms)
            #pragma unroll
            for (int nt = 0; nt < 2; ++nt)
                acc[ms][nt] = __builtin_amdgcn_mfma_f32_16x16x32_bf16(a[ms], bfr[nt], acc[ms][nt], 0, 0, 0);
    }

    // bias + store: lane holds channels ch0..ch0+3 of pixel (nt*16+l15)
    #pragma unroll
    for (int ms = 0; ms < 4; ++ms) {
        int ch0 = m0 + ms * 16 + quad * 4;
        float b0 = bv[ch0], b1v = bv[ch0 + 1], b2v = bv[ch0 + 2], b3 = bv[ch0 + 3];
        #pragma unroll
        for (int nt = 0; nt < 2; ++nt) {
            int pix = gpix0 + nt * 16 + l15;
            uint2 o;
            o.x = pack2(acc[ms][nt][0] + b0, acc[ms][nt][1] + b1v);
            o.y = pack2(acc[ms][nt][2] + b2v, acc[ms][nt][3] + b3);
            *reinterpret_cast<uint2*>(val + (size_t)pix * 256 + ch0) = o;
        }
    }
}

// ---------------------------------------------------------------------------
// k_gather: y-sorted (perm) bilinear gather + group-weighted sum -> aggb bf16
// ---------------------------------------------------------------------------
__global__ __launch_bounds__(256) void k_gather(
    const unsigned short* __restrict__ wtsb,
    const float* __restrict__ kp,
    const unsigned short* __restrict__ val,
    const int* __restrict__ perm,
    unsigned short* __restrict__ aggb)
{
    __shared__ float Wl[PIX][72];
    __shared__ float KPl[PIX][18];
    __shared__ int pixL[PIX];

    const int t = threadIdx.x;
    const int gpix0 = blockIdx.x * PIX;

    if (t < PIX) pixL[t] = perm[gpix0 + t];
    __syncthreads();

    {
        int px = t >> 3, j = t & 7;
        int pix = pixL[px];
        const unsigned short* wrow = wtsb + (size_t)pix * 72 + j * 9;
        #pragma unroll
        for (int k = 0; k < 9; ++k) Wl[px][j * 9 + k] = bf2f(wrow[k]);
        const float* krow = kp + (size_t)pix * 18;
        for (int k = j; k < 18; k += 8) KPl[px][k] = krow[k];
    }
    __syncthreads();

    const int wave = t >> 6, lane = t & 63;
    const int gl = lane >> 3;

    for (int px = wave; px < PIX; px += 4) {
        const int pix = pixL[px];
        const unsigned short* vbp = val + ((size_t)(pix >> 15) * HW) * 256 + 4 * lane;

        const float ay = KPl[px][1];
        float yf = ay * (float)H - 0.5f;
        float y0f = floorf(yf);
        float wy = yf - y0f;
        int y0 = (int)y0f;
        float vy0 = ((unsigned)y0 < (unsigned)H) ? 1.f : 0.f;
        float vy1 = ((unsigned)(y0 + 1) < (unsigned)H) ? 1.f : 0.f;
        int y0c = min(max(y0, 0), H - 1);
        int y1c = min(max(y0 + 1, 0), H - 1);

        float a0 = 0.f, a1 = 0.f, a2 = 0.f, a3 = 0.f;

        #pragma unroll
        for (int pt = 0; pt < P; ++pt) {
            float kx = KPl[px][2 * pt];
            float w  = Wl[px][gl * 9 + pt];
            float xf = kx * (float)W - 0.5f;
            float x0f = floorf(xf);
            float wx = xf - x0f;
            int x0 = (int)x0f;
            float vx0 = ((unsigned)x0 < (unsigned)W) ? 1.f : 0.f;
            float vx1 = ((unsigned)(x0 + 1) < (unsigned)W) ? 1.f : 0.f;
            int x0c = min(max(x0, 0), W - 1);
            int x1c = min(max(x0 + 1, 0), W - 1);

            float c00 = w * (1.f - wx) * (1.f - wy) * vy0 * vx0;
            float c01 = w * wx * (1.f - wy) * vy0 * vx1;
            float c10 = w * (1.f - wx) * wy * vy1 * vx0;
            float c11 = w * wx * wy * vy1 * vx1;

            uint2 u00 = *(const uint2*)(vbp + ((size_t)(y0c * W + x0c) << 8));
            uint2 u01 = *(const uint2*)(vbp + ((size_t)(y0c * W + x1c) << 8));
            uint2 u10 = *(const uint2*)(vbp + ((size_t)(y1c * W + x0c) << 8));
            uint2 u11 = *(const uint2*)(vbp + ((size_t)(y1c * W + x1c) << 8));

            a0 += c00 * __uint_as_float(u00.x << 16) + c01 * __uint_as_float(u01.x << 16)
                + c10 * __uint_as_float(u10.x << 16) + c11 * __uint_as_float(u11.x << 16);
            a1 += c00 * __uint_as_float(u00.x & 0xffff0000u) + c01 * __uint_as_float(u01.x & 0xffff0000u)
                + c10 * __uint_as_float(u10.x & 0xffff0000u) + c11 * __uint_as_float(u11.x & 0xffff0000u);
            a2 += c00 * __uint_as_float(u00.y << 16) + c01 * __uint_as_float(u01.y << 16)
                + c10 * __uint_as_float(u10.y << 16) + c11 * __uint_as_float(u11.y << 16);
            a3 += c00 * __uint_as_float(u00.y & 0xffff0000u) + c01 * __uint_as_float(u01.y & 0xffff0000u)
                + c10 * __uint_as_float(u10.y & 0xffff0000u) + c11 * __uint_as_float(u11.y & 0xffff0000u);
        }

        uint2 o;
        o.x = pack2(a0, a1);
        o.y = pack2(a2, a3);
        *reinterpret_cast<uint2*>(aggb + ((size_t)pix << 8) + 4 * lane) = o;
    }
}

// ---------------------------------------------------------------------------
// k_gemmo: out = aggb @ Wo + bo (A=WoT rows=out-channels), fp32 (b,c,hw)
// ---------------------------------------------------------------------------
__global__ __launch_bounds__(256) void k_gemmo(
    const unsigned short* __restrict__ aggb,
    const unsigned short* __restrict__ WoT,
    const float* __restrict__ bo,
    float* __restrict__ out)
{
    const int t = threadIdx.x;
    const int wave = t >> 6, lane = t & 63;
    const int n_base = blockIdx.x * 64;
    const int b = n_base >> 15;
    const int hw0 = n_base & (HW - 1);
    const int m0 = wave * 64;
    const int l15 = lane & 15, quad = lane >> 4;

    f32x4 acc[4][4];
    #pragma unroll
    for (int ms = 0; ms < 4; ++ms)
        #pragma unroll
        for (int ns = 0; ns < 4; ++ns)
            acc[ms][ns] = (f32x4){0.f, 0.f, 0.f, 0.f};

    size_t aoff[4], boff[4];
    #pragma unroll
    for (int ms = 0; ms < 4; ++ms)
        aoff[ms] = (size_t)(m0 + ms * 16 + l15) * 256 + quad * 8;
    #pragma unroll
    for (int ns = 0; ns < 4; ++ns)
        boff[ns] = (size_t)(n_base + ns * 16 + l15) * 256 + quad * 8;

    for (int kk = 0; kk < 8; ++kk) {
        bf16x8 a[4], bfr[4];
        #pragma unroll
        for (int ms = 0; ms < 4; ++ms) a[ms] = ldb8g(WoT + aoff[ms] + kk * 32);
        #pragma unroll
        for (int ns = 0; ns < 4; ++ns) bfr[ns] = ldb8g(aggb + boff[ns] + kk * 32);
        #pragma unroll
        for (int ms = 0; ms < 4; ++ms)
            #pragma unroll
            for (int ns = 0; ns < 4; ++ns)
                acc[ms][ns] = __builtin_amdgcn_mfma_f32_16x16x32_bf16(a[ms], bfr[ns], acc[ms][ns], 0, 0, 0);
    }

    float bor[4][4];
    #pragma unroll
    for (int ms = 0; ms < 4; ++ms)
        #pragma unroll
        for (int r = 0; r < 4; ++r)
            bor[ms][r] = bo[m0 + ms * 16 + quad * 4 + r];

    #pragma unroll
    for (int ms = 0; ms < 4; ++ms) {
        #pragma unroll
        for (int ns = 0; ns < 4; ++ns) {
            #pragma unroll
            for (int r = 0; r < 4; ++r) {
                int ch = m0 + ms * 16 + quad * 4 + r;
                out[((size_t)b * 256 + ch) * HW + hw0 + ns * 16 + l15] = acc[ms][ns][r] + bor[ms][r];
            }
        }
    }
}

// ---------------------------------------------------------------------------
extern "C" void kernel_launch(void* const* d_in, const int* in_sizes, int n_in,
                              void* d_out, int out_size, void* d_ws, size_t ws_size,
                              hipStream_t stream)
{
    const float* feats1 = (const float*)d_in[0];
    const float* feats2 = (const float*)d_in[1];
    const float* anchor = (const float*)d_in[2];
    const float* n1g    = (const float*)d_in[3];
    const float* n1b    = (const float*)d_in[4];
    const float* n2g    = (const float*)d_in[5];
    const float* n2b    = (const float*)d_in[6];
    const float* Wv     = (const float*)d_in[7];
    const float* bv     = (const float*)d_in[8];
    const float* Ww     = (const float*)d_in[9];
    const float* bw     = (const float*)d_in[10];
    const float* Wk     = (const float*)d_in[11];
    const float* bk     = (const float*)d_in[12];
    const float* Wo     = (const float*)d_in[13];
    const float* bo     = (const float*)d_in[14];

    float* out = (float*)d_out;
    float* kp  = out + (size_t)B * C * HW;

    char* ws = (char*)d_ws;
    unsigned short* val  = (unsigned short*)(ws);
    unsigned short* aggb = (unsigned short*)(ws + 33554432);
    unsigned short* wtsb = (unsigned short*)(ws + 67108864);
    unsigned short* WwT  = (unsigned short*)(ws + 76546048);
    unsigned short* WvT  = (unsigned short*)(ws + 76587008);
    unsigned short* WoT  = (unsigned short*)(ws + 76718080);
    int* perm   = (int*)(ws + 76849152);
    int* hist   = (int*)(ws + 77111296);
    int* cursor = hist + NBKT;

    hipMemsetAsync(hist, 0, NBKT * sizeof(int), stream);
    k_prep   <<<592,  256, 0, stream>>>(Ww, Wv, Wo, WwT, WvT, WoT);
    k_hist   <<<256,  256, 0, stream>>>(anchor, hist);
    k_scan   <<<1,    256, 0, stream>>>(hist, cursor);
    k_scatter<<<256,  256, 0, stream>>>(anchor, cursor, perm);
    kA       <<<2048, 256, 0, stream>>>(feats1, anchor, n1g, n1b, Wk, bk, WwT, bw, wtsb, kp);
    kB       <<<2048, 256, 0, stream>>>(feats2, n2g, n2b, WvT, bv, val);
    k_gather <<<2048, 256, 0, stream>>>(wtsb, kp, val, perm, aggb);
    k_gemmo  <<<1024, 256, 0, stream>>>(aggb, WoT, bo, out);
}

// Round 4
// 406.937 us; speedup vs baseline: 1.1786x; 1.1786x over previous
//
#include <hip/hip_runtime.h>
#include <hip/hip_bf16.h>

// Deformable1DFeatureAggregator on MI355X (gfx950) — round 3
// Kernels (8 dispatches, no memset):
//   k_prep    : Ww/Wv/Wo -> bf16 N x K (WwT 80 rows, zero-padded)
//   k_hist    : per-block LDS histogram of (batch,y0) -> hist64[64][258] (plain stores)
//   k_scan    : bucket totals + exclusive base + per-(block,bucket) offsets
//   k_scatter : LDS-cursor scatter -> perm[] (y-sorted pixel ids)
//   kA        : LN1 + fp32 Wk offsets -> kp; MFMA logits + softmax -> wts bf16
//   kB        : LN2 + gemmV (A=WvT, channel-major acc) -> val bf16
//   k_gather  : XCD-swizzled y-sorted bilinear gather (pk-fma) -> aggb bf16
//   k_gemmo   : out = Wo^T-gemm(aggb) + bo -> fp32 (b,c,h,w)
//
// ws layout (bytes):
//   [0)            val   bf16 65536x256   33,554,432
//   [33554432)     aggb  bf16 65536x256   33,554,432
//   [67108864)     wts   bf16 65536x72     9,437,184
//   [76546048)     WwT   bf16 80x256          40,960
//   [76587008)     WvT   bf16 256x256        131,072
//   [76718080)     WoT   bf16 256x256        131,072
//   [76849152)     perm  int32 65536         262,144
//   [77111296)     hist64 int32 64x258       264,192* (258 used/row)
//   [77375488)     off    int32 64x258       264,192

constexpr int B = 2, C = 256, H = 128, W = 256;
constexpr int HW = H * W;            // 32768
constexpr int P = 9, G = 8;
constexpr int PIX = 32;
constexpr int NPIX = B * HW;         // 65536
constexpr int NBKT = 2 * 129;        // 258

typedef __attribute__((ext_vector_type(8))) __bf16 bf16x8;
typedef __attribute__((ext_vector_type(4))) float f32x4;
typedef __attribute__((ext_vector_type(2))) float f32x2;

static __device__ __forceinline__ unsigned short f2bf(float x) {
    __hip_bfloat16 h = __float2bfloat16(x);
    return *reinterpret_cast<unsigned short*>(&h);
}
static __device__ __forceinline__ unsigned int pack2(float a, float b) {
    return (unsigned int)f2bf(a) | ((unsigned int)f2bf(b) << 16);
}
static __device__ __forceinline__ float bf2f(unsigned short u) {
    return __uint_as_float((unsigned int)u << 16);
}
static __device__ __forceinline__ bf16x8 ldb8g(const unsigned short* p) {
    return *reinterpret_cast<const bf16x8*>(p);
}

// ---------------------------------------------------------------------------
__global__ __launch_bounds__(256) void k_prep(
    const float* __restrict__ Ww, const float* __restrict__ Wv,
    const float* __restrict__ Wo,
    unsigned short* __restrict__ WwT, unsigned short* __restrict__ WvT,
    unsigned short* __restrict__ WoT)
{
    int tid = blockIdx.x * 256 + threadIdx.x;   // 592 blocks = 151552 threads
    if (tid < 20480) {
        int n = tid >> 8, k = tid & 255;
        WwT[tid] = f2bf((n < 72) ? Ww[k * 72 + n] : 0.f);
    } else if (tid < 20480 + 65536) {
        int i = tid - 20480;
        int n = i >> 8, k = i & 255;
        WvT[i] = f2bf(Wv[k * 256 + n]);
    } else {
        int i = tid - 86016;
        int n = i >> 8, k = i & 255;
        WoT[i] = f2bf(Wo[k * 256 + n]);
    }
}

// ---------------------------------------------------------------------------
static __device__ __forceinline__ int bucket_of(const float* anchor, int pix) {
    float ay = anchor[(size_t)pix * 2 + 1];
    int y0 = (int)floorf(ay * (float)H - 0.5f);
    y0 = min(max(y0, -1), H - 1);
    return (pix >> 15) * 129 + y0 + 1;
}

// per-block LDS histogram -> hist64 rows (no global atomics)
__global__ __launch_bounds__(1024) void k_hist(
    const float* __restrict__ anchor, int* __restrict__ hist64)
{
    __shared__ int h[NBKT];
    const int t = threadIdx.x, blk = blockIdx.x;
    for (int i = t; i < NBKT; i += 1024) h[i] = 0;
    __syncthreads();
    atomicAdd(&h[bucket_of(anchor, blk * 1024 + t)], 1);
    __syncthreads();
    for (int i = t; i < NBKT; i += 1024) hist64[blk * NBKT + i] = h[i];
}

// bucket totals -> exclusive base -> off[blk][bkt] = base + column prefix
__global__ __launch_bounds__(256) void k_scan(
    const int* __restrict__ hist64, int* __restrict__ off)
{
    __shared__ int tot[NBKT], base[NBKT];
    const int t = threadIdx.x;
    for (int bkt = t; bkt < NBKT; bkt += 256) {
        int run = 0;
        for (int blk = 0; blk < 64; ++blk) run += hist64[blk * NBKT + bkt];
        tot[bkt] = run;
    }
    __syncthreads();
    if (t == 0) {
        int run = 0;
        for (int i = 0; i < NBKT; ++i) { base[i] = run; run += tot[i]; }
    }
    __syncthreads();
    for (int bkt = t; bkt < NBKT; bkt += 256) {
        int run = base[bkt];
        for (int blk = 0; blk < 64; ++blk) {
            int v = hist64[blk * NBKT + bkt];
            off[blk * NBKT + bkt] = run;
            run += v;
        }
    }
}

// scatter with LDS cursors only
__global__ __launch_bounds__(1024) void k_scatter(
    const float* __restrict__ anchor, const int* __restrict__ off,
    int* __restrict__ perm)
{
    __shared__ int cur[NBKT];
    const int t = threadIdx.x, blk = blockIdx.x;
    for (int i = t; i < NBKT; i += 1024) cur[i] = off[blk * NBKT + i];
    __syncthreads();
    int pix = blk * 1024 + t;
    int pos = atomicAdd(&cur[bucket_of(anchor, pix)], 1);
    perm[pos] = pix;
}

// ---------------------------------------------------------------------------
// kA: LN1 + fp32 Wk offsets -> kp; MFMA logits (80-col WwT) + softmax -> wts bf16
// ---------------------------------------------------------------------------
__global__ __launch_bounds__(256) void kA(
    const float* __restrict__ feats1, const float* __restrict__ anchor,
    const float* __restrict__ g1, const float* __restrict__ b1,
    const float* __restrict__ Wk, const float* __restrict__ bk,
    const unsigned short* __restrict__ WwT, const float* __restrict__ bw,
    unsigned short* __restrict__ wtsb, float* __restrict__ kp_out)
{
    __shared__ unsigned short Hi[PIX][264];
    __shared__ __align__(16) char smB[20480];
    __shared__ float meanA[PIX], rstdA[PIX], axL[PIX], ayL[PIX];

    float* WkL  = (float*)smB;              // [256*9]
    float* red2 = (float*)(smB + 9216);     // [8*32*9]
    float* red  = (float*)(smB + 18432);    // [2*256]
    float* Lg   = (float*)smB;              // [32*81] alias (post-MFMA)

    const int t = threadIdx.x;
    const int p = t & 31;
    const int part = t >> 5;
    const int gpix0 = blockIdx.x * PIX;
    const int b = gpix0 >> 15;
    const int n0 = gpix0 & (HW - 1);
    const float* Fb = feats1 + (size_t)b * C * HW;

    for (int i = t; i < 2304; i += 256) WkL[i] = Wk[i];
    if (t < PIX) {
        axL[t] = anchor[((size_t)gpix0 + t) * 2 + 0];
        ayL[t] = anchor[((size_t)gpix0 + t) * 2 + 1];
    }

    float x[32];
    #pragma unroll
    for (int i = 0; i < 32; ++i)
        x[i] = Fb[(size_t)(part * 32 + i) * HW + n0 + p];

    float s = 0.f, ss = 0.f;
    #pragma unroll
    for (int i = 0; i < 32; ++i) { s += x[i]; ss += x[i] * x[i]; }
    red[part * 32 + p] = s;
    red[256 + part * 32 + p] = ss;
    __syncthreads();
    if (part == 0) {
        float s2 = 0.f, ss2 = 0.f;
        #pragma unroll
        for (int k = 0; k < 8; ++k) { s2 += red[k * 32 + p]; ss2 += red[256 + k * 32 + p]; }
        float mean = s2 * (1.f / C);
        float var  = ss2 * (1.f / C) - mean * mean;
        meanA[p] = mean; rstdA[p] = rsqrtf(var + 1e-5f);
    }
    __syncthreads();

    {
        float mean = meanA[p], rstd = rstdA[p];
        #pragma unroll
        for (int i = 0; i < 32; ++i) {
            int c = part * 32 + i;
            x[i] = (x[i] - mean) * rstd * g1[c] + b1[c];
        }
    }

    {
        float po[9];
        #pragma unroll
        for (int pt = 0; pt < 9; ++pt) po[pt] = 0.f;
        #pragma unroll 4
        for (int i = 0; i < 32; ++i) {
            int c = part * 32 + i;
            float xv = x[i];
            #pragma unroll
            for (int pt = 0; pt < 9; ++pt) po[pt] += xv * WkL[c * 9 + pt];
        }
        #pragma unroll
        for (int pt = 0; pt < 9; ++pt) red2[(part * 32 + p) * 9 + pt] = po[pt];
    }

    {
        unsigned int* row = (unsigned int*)&Hi[p][part * 32];
        #pragma unroll
        for (int i = 0; i < 16; ++i) row[i] = pack2(x[2 * i], x[2 * i + 1]);
    }
    __syncthreads();

    for (int tau = t; tau < 288; tau += 256) {
        int px = tau & 31, pt = tau >> 5;
        float offv = bk[pt];
        #pragma unroll
        for (int k = 0; k < 8; ++k) offv += red2[(k * 32 + px) * 9 + pt];
        size_t o = (((size_t)gpix0 + px) * P + pt) * 2;
        kp_out[o] = axL[px] + offv;
        kp_out[o + 1] = ayL[px];
    }

    const int wave = t >> 6, lane = t & 63;
    const int l15 = lane & 15, quad = lane >> 4;
    const int mt = wave & 1;
    const int ntb = (wave >> 1) * 3;
    const int ntc = (wave >> 1) ? 2 : 3;

    f32x4 acc[3];
    #pragma unroll
    for (int j = 0; j < 3; ++j) acc[j] = (f32x4){0.f, 0.f, 0.f, 0.f};

    const unsigned short* arow = &Hi[mt * 16 + l15][quad * 8];
    for (int kk = 0; kk < 8; ++kk) {
        bf16x8 a = *reinterpret_cast<const bf16x8*>(arow + kk * 32);
        for (int j = 0; j < 3; ++j) {
            if (j < ntc) {
                bf16x8 bfr = ldb8g(WwT + (size_t)((ntb + j) * 16 + l15) * 256 + quad * 8 + kk * 32);
                acc[j] = __builtin_amdgcn_mfma_f32_16x16x32_bf16(a, bfr, acc[j], 0, 0, 0);
            }
        }
    }
    __syncthreads();   // red2/WkL dead; Lg alias safe

    #pragma unroll
    for (int j = 0; j < 3; ++j) {
        if (j < ntc) {
            int n = (ntb + j) * 16 + l15;
            if (n < 72) {
                float bwn = bw[n];
                #pragma unroll
                for (int r = 0; r < 4; ++r)
                    Lg[(mt * 16 + quad * 4 + r) * 81 + n] = acc[j][r] + bwn;
            }
        }
    }
    __syncthreads();

    {
        int px = t >> 3, g = t & 7;
        float m = -1e30f;
        #pragma unroll
        for (int pt = 0; pt < P; ++pt) m = fmaxf(m, Lg[px * 81 + pt * 8 + g]);
        float e[P], sum = 0.f;
        #pragma unroll
        for (int pt = 0; pt < P; ++pt) { e[pt] = __expf(Lg[px * 81 + pt * 8 + g] - m); sum += e[pt]; }
        float inv = 1.f / sum;
        unsigned short* wb = wtsb + ((size_t)gpix0 + px) * 72 + g * 9;
        #pragma unroll
        for (int pt = 0; pt < P; ++pt) wb[pt] = f2bf(e[pt] * inv);
    }
}

// ---------------------------------------------------------------------------
// kB: LN2 + gemmV (A=WvT so lane accs = 4 consecutive channels -> uint2 store)
// ---------------------------------------------------------------------------
__global__ __launch_bounds__(256) void kB(
    const float* __restrict__ feats2,
    const float* __restrict__ g2, const float* __restrict__ b2,
    const unsigned short* __restrict__ WvT, const float* __restrict__ bv,
    unsigned short* __restrict__ val)
{
    __shared__ unsigned short Hi[PIX][264];
    __shared__ float red[2][8][PIX];
    __shared__ float meanA[PIX], rstdA[PIX];

    const int t = threadIdx.x;
    const int p = t & 31;
    const int part = t >> 5;
    const int gpix0 = blockIdx.x * PIX;
    const int b = gpix0 >> 15;
    const int n0 = gpix0 & (HW - 1);
    const float* Fb = feats2 + (size_t)b * C * HW;

    float x[32];
    #pragma unroll
    for (int i = 0; i < 32; ++i)
        x[i] = Fb[(size_t)(part * 32 + i) * HW + n0 + p];

    float s = 0.f, ss = 0.f;
    #pragma unroll
    for (int i = 0; i < 32; ++i) { s += x[i]; ss += x[i] * x[i]; }
    red[0][part][p] = s; red[1][part][p] = ss;
    __syncthreads();
    if (part == 0) {
        float s2 = 0.f, ss2 = 0.f;
        #pragma unroll
        for (int k = 0; k < 8; ++k) { s2 += red[0][k][p]; ss2 += red[1][k][p]; }
        float mean = s2 * (1.f / C);
        float var  = ss2 * (1.f / C) - mean * mean;
        meanA[p] = mean; rstdA[p] = rsqrtf(var + 1e-5f);
    }
    __syncthreads();
    {
        float mean = meanA[p], rstd = rstdA[p];
        unsigned int* row = (unsigned int*)&Hi[p][part * 32];
        #pragma unroll
        for (int i = 0; i < 16; ++i) {
            float v0 = (x[2 * i] - mean) * rstd * g2[part * 32 + 2 * i] + b2[part * 32 + 2 * i];
            float v1 = (x[2 * i + 1] - mean) * rstd * g2[part * 32 + 2 * i + 1] + b2[part * 32 + 2 * i + 1];
            row[i] = pack2(v0, v1);
        }
    }
    __syncthreads();

    const int wave = t >> 6, lane = t & 63;
    const int l15 = lane & 15, quad = lane >> 4;
    const int m0 = wave * 64;

    f32x4 acc[4][2];
    #pragma unroll
    for (int ms = 0; ms < 4; ++ms)
        #pragma unroll
        for (int nt = 0; nt < 2; ++nt)
            acc[ms][nt] = (f32x4){0.f, 0.f, 0.f, 0.f};

    for (int kk = 0; kk < 8; ++kk) {
        bf16x8 a[4], bfr[2];
        #pragma unroll
        for (int ms = 0; ms < 4; ++ms)
            a[ms] = ldb8g(WvT + (size_t)(m0 + ms * 16 + l15) * 256 + quad * 8 + kk * 32);
        #pragma unroll
        for (int nt = 0; nt < 2; ++nt)
            bfr[nt] = *reinterpret_cast<const bf16x8*>(&Hi[nt * 16 + l15][quad * 8 + kk * 32]);
        #pragma unroll
        for (int ms = 0; ms < 4; ++ms)
            #pragma unroll
            for (int nt = 0; nt < 2; ++nt)
                acc[ms][nt] = __builtin_amdgcn_mfma_f32_16x16x32_bf16(a[ms], bfr[nt], acc[ms][nt], 0, 0, 0);
    }

    #pragma unroll
    for (int ms = 0; ms < 4; ++ms) {
        int ch0 = m0 + ms * 16 + quad * 4;
        float b0 = bv[ch0], b1v = bv[ch0 + 1], b2v = bv[ch0 + 2], b3 = bv[ch0 + 3];
        #pragma unroll
        for (int nt = 0; nt < 2; ++nt) {
            int pix = gpix0 + nt * 16 + l15;
            uint2 o;
            o.x = pack2(acc[ms][nt][0] + b0, acc[ms][nt][1] + b1v);
            o.y = pack2(acc[ms][nt][2] + b2v, acc[ms][nt][3] + b3);
            *reinterpret_cast<uint2*>(val + (size_t)pix * 256 + ch0) = o;
        }
    }
}

// ---------------------------------------------------------------------------
// k_gather: XCD-swizzled, y-sorted bilinear gather, pk-fma accumulate
// ---------------------------------------------------------------------------
__global__ __launch_bounds__(256) void k_gather(
    const unsigned short* __restrict__ wtsb,
    const float* __restrict__ kp,
    const unsigned short* __restrict__ val,
    const int* __restrict__ perm,
    unsigned short* __restrict__ aggb)
{
    __shared__ float Wl[PIX][72];
    __shared__ float KPl[PIX][18];
    __shared__ int pixL[PIX];

    const int t = threadIdx.x;
    // XCD swizzle: XCD (phys%8) gets contiguous sorted range -> L2-local y-window
    const int phys = blockIdx.x;
    const int lb = (phys & 7) * 256 + (phys >> 3);
    const int gpix0 = lb * PIX;

    if (t < PIX) pixL[t] = perm[gpix0 + t];
    __syncthreads();

    {
        int px = t >> 3, j = t & 7;
        int pix = pixL[px];
        const unsigned short* wrow = wtsb + (size_t)pix * 72 + j * 9;
        #pragma unroll
        for (int k = 0; k < 9; ++k) Wl[px][j * 9 + k] = bf2f(wrow[k]);
        const float* krow = kp + (size_t)pix * 18;
        for (int k = j; k < 18; k += 8) KPl[px][k] = krow[k];
    }
    __syncthreads();

    const int wave = t >> 6, lane = t & 63;
    const int gl = lane >> 3;

    for (int px = wave; px < PIX; px += 4) {
        const int pix = pixL[px];
        const unsigned short* vbp = val + ((size_t)(pix >> 15) * HW) * 256 + 4 * lane;

        const float ay = KPl[px][1];
        float yf = ay * (float)H - 0.5f;
        float y0f = floorf(yf);
        float wy = yf - y0f;
        int y0 = (int)y0f;
        float e0 = (((unsigned)y0 < (unsigned)H) ? 1.f : 0.f) * (1.f - wy);
        float e1 = (((unsigned)(y0 + 1) < (unsigned)H) ? 1.f : 0.f) * wy;
        int yb0 = min(max(y0, 0), H - 1) * W;
        int yb1 = min(max(y0 + 1, 0), H - 1) * W;

        f32x2 a01 = (f32x2){0.f, 0.f};
        f32x2 a23 = (f32x2){0.f, 0.f};

        #pragma unroll
        for (int pt = 0; pt < P; ++pt) {
            float kx = KPl[px][2 * pt];
            float w  = Wl[px][gl * 9 + pt];
            float xf = kx * (float)W - 0.5f;
            float x0f = floorf(xf);
            float wx = xf - x0f;
            int x0 = (int)x0f;
            float t0 = w * (1.f - wx) * (((unsigned)x0 < (unsigned)W) ? 1.f : 0.f);
            float t1 = w * wx * (((unsigned)(x0 + 1) < (unsigned)W) ? 1.f : 0.f);
            int x0c = min(max(x0, 0), W - 1);
            int x1c = min(max(x0 + 1, 0), W - 1);

            float c00 = t0 * e0, c01 = t1 * e0, c10 = t0 * e1, c11 = t1 * e1;

            uint2 u00 = *(const uint2*)(vbp + ((size_t)(yb0 + x0c) << 8));
            uint2 u01 = *(const uint2*)(vbp + ((size_t)(yb0 + x1c) << 8));
            uint2 u10 = *(const uint2*)(vbp + ((size_t)(yb1 + x0c) << 8));
            uint2 u11 = *(const uint2*)(vbp + ((size_t)(yb1 + x1c) << 8));

            f32x2 v;
            v.x = __uint_as_float(u00.x << 16); v.y = __uint_as_float(u00.x & 0xffff0000u);
            a01 += v * c00;
            v.x = __uint_as_float(u00.y << 16); v.y = __uint_as_float(u00.y & 0xffff0000u);
            a23 += v * c00;
            v.x = __uint_as_float(u01.x << 16); v.y = __uint_as_float(u01.x & 0xffff0000u);
            a01 += v * c01;
            v.x = __uint_as_float(u01.y << 16); v.y = __uint_as_float(u01.y & 0xffff0000u);
            a23 += v * c01;
            v.x = __uint_as_float(u10.x << 16); v.y = __uint_as_float(u10.x & 0xffff0000u);
            a01 += v * c10;
            v.x = __uint_as_float(u10.y << 16); v.y = __uint_as_float(u10.y & 0xffff0000u);
            a23 += v * c10;
            v.x = __uint_as_float(u11.x << 16); v.y = __uint_as_float(u11.x & 0xffff0000u);
            a01 += v * c11;
            v.x = __uint_as_float(u11.y << 16); v.y = __uint_as_float(u11.y & 0xffff0000u);
            a23 += v * c11;
        }

        uint2 o;
        o.x = pack2(a01.x, a01.y);
        o.y = pack2(a23.x, a23.y);
        *reinterpret_cast<uint2*>(aggb + ((size_t)pix << 8) + 4 * lane) = o;
    }
}

// ---------------------------------------------------------------------------
// k_gemmo: out = aggb @ Wo + bo (A=WoT rows=out-channels), fp32 (b,c,hw)
// ---------------------------------------------------------------------------
__global__ __launch_bounds__(256) void k_gemmo(
    const unsigned short* __restrict__ aggb,
    const unsigned short* __restrict__ WoT,
    const float* __restrict__ bo,
    float* __restrict__ out)
{
    const int t = threadIdx.x;
    const int wave = t >> 6, lane = t & 63;
    const int n_base = blockIdx.x * 64;
    const int b = n_base >> 15;
    const int hw0 = n_base & (HW - 1);
    const int m0 = wave * 64;
    const int l15 = lane & 15, quad = lane >> 4;

    f32x4 acc[4][4];
    #pragma unroll
    for (int ms = 0; ms < 4; ++ms)
        #pragma unroll
        for (int ns = 0; ns < 4; ++ns)
            acc[ms][ns] = (f32x4){0.f, 0.f, 0.f, 0.f};

    size_t aoff[4], boff[4];
    #pragma unroll
    for (int ms = 0; ms < 4; ++ms)
        aoff[ms] = (size_t)(m0 + ms * 16 + l15) * 256 + quad * 8;
    #pragma unroll
    for (int ns = 0; ns < 4; ++ns)
        boff[ns] = (size_t)(n_base + ns * 16 + l15) * 256 + quad * 8;

    for (int kk = 0; kk < 8; ++kk) {
        bf16x8 a[4], bfr[4];
        #pragma unroll
        for (int ms = 0; ms < 4; ++ms) a[ms] = ldb8g(WoT + aoff[ms] + kk * 32);
        #pragma unroll
        for (int ns = 0; ns < 4; ++ns) bfr[ns] = ldb8g(aggb + boff[ns] + kk * 32);
        #pragma unroll
        for (int ms = 0; ms < 4; ++ms)
            #pragma unroll
            for (int ns = 0; ns < 4; ++ns)
                acc[ms][ns] = __builtin_amdgcn_mfma_f32_16x16x32_bf16(a[ms], bfr[ns], acc[ms][ns], 0, 0, 0);
    }

    float bor[4][4];
    #pragma unroll
    for (int ms = 0; ms < 4; ++ms)
        #pragma unroll
        for (int r = 0; r < 4; ++r)
            bor[ms][r] = bo[m0 + ms * 16 + quad * 4 + r];

    #pragma unroll
    for (int ms = 0; ms < 4; ++ms) {
        #pragma unroll
        for (int ns = 0; ns < 4; ++ns) {
            #pragma unroll
            for (int r = 0; r < 4; ++r) {
                int ch = m0 + ms * 16 + quad * 4 + r;
                out[((size_t)b * 256 + ch) * HW + hw0 + ns * 16 + l15] = acc[ms][ns][r] + bor[ms][r];
            }
        }
    }
}

// ---------------------------------------------------------------------------
extern "C" void kernel_launch(void* const* d_in, const int* in_sizes, int n_in,
                              void* d_out, int out_size, void* d_ws, size_t ws_size,
                              hipStream_t stream)
{
    const float* feats1 = (const float*)d_in[0];
    const float* feats2 = (const float*)d_in[1];
    const float* anchor = (const float*)d_in[2];
    const float* n1g    = (const float*)d_in[3];
    const float* n1b    = (const float*)d_in[4];
    const float* n2g    = (const float*)d_in[5];
    const float* n2b    = (const float*)d_in[6];
    const float* Wv     = (const float*)d_in[7];
    const float* bv     = (const float*)d_in[8];
    const float* Ww     = (const float*)d_in[9];
    const float* bw     = (const float*)d_in[10];
    const float* Wk     = (const float*)d_in[11];
    const float* bk     = (const float*)d_in[12];
    const float* Wo     = (const float*)d_in[13];
    const float* bo     = (const float*)d_in[14];

    float* out = (float*)d_out;
    float* kp  = out + (size_t)B * C * HW;

    char* ws = (char*)d_ws;
    unsigned short* val  = (unsigned short*)(ws);
    unsigned short* aggb = (unsigned short*)(ws + 33554432);
    unsigned short* wtsb = (unsigned short*)(ws + 67108864);
    unsigned short* WwT  = (unsigned short*)(ws + 76546048);
    unsigned short* WvT  = (unsigned short*)(ws + 76587008);
    unsigned short* WoT  = (unsigned short*)(ws + 76718080);
    int* perm   = (int*)(ws + 76849152);
    int* hist64 = (int*)(ws + 77111296);
    int* off    = (int*)(ws + 77375488);

    k_prep   <<<592,  256,  0, stream>>>(Ww, Wv, Wo, WwT, WvT, WoT);
    k_hist   <<<64,   1024, 0, stream>>>(anchor, hist64);
    k_scan   <<<1,    256,  0, stream>>>(hist64, off);
    k_scatter<<<64,   1024, 0, stream>>>(anchor, off, perm);
    kA       <<<2048, 256,  0, stream>>>(feats1, anchor, n1g, n1b, Wk, bk, WwT, bw, wtsb, kp);
    kB       <<<2048, 256,  0, stream>>>(feats2, n2g, n2b, WvT, bv, val);
    k_gather <<<2048, 256,  0, stream>>>(wtsb, kp, val, perm, aggb);
    k_gemmo  <<<1024, 256,  0, stream>>>(aggb, WoT, bo, out);
}